// Round 1
// baseline (570.793 us; speedup 1.0000x reference)
//
#include <hip/hip_runtime.h>

#define DIM 256
#define NC 12

typedef __attribute__((ext_vector_type(8))) short short8;
typedef __attribute__((ext_vector_type(4))) float f32x4;

__device__ __forceinline__ short f32bf(float f) {
    unsigned u = __builtin_bit_cast(unsigned, f);
    unsigned r = u + 0x7FFFu + ((u >> 16) & 1u);
    return (short)(r >> 16);
}

// ---------------------------------------------------------------- prep ------
// blocks 0..1023   : bank row fp64 norms + normalized bf16 bank (pad rows 1000..1023 -> 0)
// blocks 1024..1535: W1 -> bf16
// blocks 1536..1791: W2 -> bf16
__global__ __launch_bounds__(256) void k_prep(const float* __restrict__ bank,
        const float* __restrict__ W1, const float* __restrict__ W2,
        short* __restrict__ bnbf, double* __restrict__ binv,
        short* __restrict__ w1bf, short* __restrict__ w2bf)
{
    __shared__ double part[4];
    __shared__ double s_inv;
    const int bid = blockIdx.x, t = threadIdx.x;
    if (bid < 1024) {
        const int row = bid;
        if (row < 1000) {
            float v = bank[(size_t)row * DIM + t];
            double ssq = (double)v * (double)v;
            for (int o = 32; o > 0; o >>= 1) ssq += __shfl_down(ssq, o);
            if ((t & 63) == 0) part[t >> 6] = ssq;
            __syncthreads();
            if (t == 0) {
                double s = part[0] + part[1] + part[2] + part[3];
                double n = sqrt(s); if (n < 1e-12) n = 1e-12;
                double inv = 1.0 / n;
                binv[row] = inv; s_inv = inv;
            }
            __syncthreads();
            bnbf[(size_t)row * DIM + t] = f32bf((float)((double)v * s_inv));
        } else {
            bnbf[(size_t)row * DIM + t] = 0;
            if (t == 0) binv[row] = 0.0;
        }
    } else if (bid < 1536) {
        const int i = (bid - 1024) * 256 + t;
        w1bf[i] = f32bf(W1[i]);
    } else {
        const int i = (bid - 1536) * 256 + t;
        w2bf[i] = f32bf(W2[i]);
    }
}

// ------------------------------------------------------------ preselect -----
// 64 queries/block, 16 bank tiles of 64. bf16 MFMA sims (raw q: q-norm is
// ranking-invariant). Per-thread register top-12 over a strided quarter of
// each tile row; LDS merge -> global top-12 indices per query.
__global__ __launch_bounds__(256) void k_presel(const float* __restrict__ feat,
        const short* __restrict__ bnbf, int* __restrict__ top)
{
    __shared__ alignas(16) char smemA[64 * 264 * 2];   // q bf16 [64][264]; later cand merge area
    __shared__ alignas(16) char smemB[64 * 264 * 2];   // bank bf16 [64][264]; alias sims f32 [64][68]
    short* qbf   = (short*)smemA;
    float* candv = (float*)smemA;
    int*   candi = (int*)(smemA + 64 * 48 * 4);
    short* bB    = (short*)smemB;
    float* sims  = (float*)smemB;

    const int t = threadIdx.x;
    const int lane = t & 63;
    const int w = t >> 6;
    const int qbase = blockIdx.x * 64;
    const int r = t >> 2, p = t & 3;

    // stage raw q as bf16
    {
        const float4* src = (const float4*)(feat + (size_t)(qbase + r) * DIM + p * 64);
        short* dst = qbf + r * 264 + p * 64;
        #pragma unroll
        for (int i = 0; i < 16; ++i) {
            float4 v = src[i];
            dst[i*4+0] = f32bf(v.x); dst[i*4+1] = f32bf(v.y);
            dst[i*4+2] = f32bf(v.z); dst[i*4+3] = f32bf(v.w);
        }
    }

    float tv[NC]; int ti[NC];
    #pragma unroll
    for (int i = 0; i < NC; ++i) { tv[i] = -3e38f; ti[i] = -1; }
    float tmin = -3e38f;

    const int mbase = (w >> 1) * 32;
    const int nbase = (w & 1) * 32;
    const f32x4 vzero = {0.f, 0.f, 0.f, 0.f};

    __syncthreads();

    for (int tile = 0; tile < 16; ++tile) {
        // stage bank tile [64][256] bf16
        {
            const uint4* bsrc = (const uint4*)(bnbf + (size_t)(tile * 64 + r) * DIM + p * 64);
            uint4* bdst = (uint4*)((char*)bB + r * 528 + p * 128);
            #pragma unroll
            for (int i = 0; i < 8; ++i) bdst[i] = bsrc[i];
        }
        __syncthreads();

        f32x4 acc[2][2];
        acc[0][0] = vzero; acc[0][1] = vzero; acc[1][0] = vzero; acc[1][1] = vzero;
        #pragma unroll
        for (int kc = 0; kc < 8; ++kc) {
            const int ko = kc * 32 + ((lane >> 4) << 3);
            short8 a0 = *(const short8*)(qbf + (mbase +      (lane & 15)) * 264 + ko);
            short8 a1 = *(const short8*)(qbf + (mbase + 16 + (lane & 15)) * 264 + ko);
            short8 b0 = *(const short8*)(bB  + (nbase +      (lane & 15)) * 264 + ko);
            short8 b1 = *(const short8*)(bB  + (nbase + 16 + (lane & 15)) * 264 + ko);
            acc[0][0] = __builtin_amdgcn_mfma_f32_16x16x32_bf16(a0, b0, acc[0][0], 0, 0, 0);
            acc[0][1] = __builtin_amdgcn_mfma_f32_16x16x32_bf16(a0, b1, acc[0][1], 0, 0, 0);
            acc[1][0] = __builtin_amdgcn_mfma_f32_16x16x32_bf16(a1, b0, acc[1][0], 0, 0, 0);
            acc[1][1] = __builtin_amdgcn_mfma_f32_16x16x32_bf16(a1, b1, acc[1][1], 0, 0, 0);
        }
        __syncthreads();
        // dump C-frags: row=(lane>>4)*4+rr, col=lane&15
        {
            const int rq = (lane >> 4) << 2;
            const int cc = lane & 15;
            #pragma unroll
            for (int mt = 0; mt < 2; ++mt)
                #pragma unroll
                for (int nt = 0; nt < 2; ++nt) {
                    const int rowb = mbase + mt * 16 + rq;
                    const int colb = nbase + nt * 16 + cc;
                    #pragma unroll
                    for (int rr = 0; rr < 4; ++rr)
                        sims[(rowb + rr) * 68 + colb] = acc[mt][nt][rr];
                }
        }
        __syncthreads();
        // scan my 16 columns of my query's row
        {
            const int cb = p * 16;
            #pragma unroll
            for (int j = 0; j < 16; ++j) {
                float v = sims[r * 68 + cb + j];
                int idx = tile * 64 + cb + j;
                if (idx < 1000 && v > tmin) {
                    int ms = 0; float mv = tv[0];
                    #pragma unroll
                    for (int s = 1; s < NC; ++s) if (tv[s] < mv) { mv = tv[s]; ms = s; }
                    #pragma unroll
                    for (int s = 0; s < NC; ++s) if (s == ms) { tv[s] = v; ti[s] = idx; }
                    float nm = tv[0];
                    #pragma unroll
                    for (int s = 1; s < NC; ++s) nm = fminf(nm, tv[s]);
                    tmin = nm;
                }
            }
        }
        __syncthreads();
    }

    // merge 4 x top-12 -> top-12 per query
    #pragma unroll
    for (int s = 0; s < NC; ++s) {
        candv[r * 48 + p * NC + s] = tv[s];
        candi[r * 48 + p * NC + s] = ti[s];
    }
    __syncthreads();
    if (t < 64) {
        const int q = t;
        for (int k = 0; k < NC; ++k) {
            float best = -3e38f; int bs = 0;
            for (int j = 0; j < 48; ++j) {
                float x = candv[q * 48 + j];
                if (x > best) { best = x; bs = j; }
            }
            top[(size_t)(qbase + q) * NC + k] = candi[q * 48 + bs];
            candv[q * 48 + bs] = -3e38f;
        }
    }
}

// -------------------------------------------------------------- refine ------
// fp64 re-computation of the 12 candidate cosine sims, exact top-5, softmax,
// nf = sum w_k * bank_row_k  -> bf16. 64 queries/block, 4 threads/query.
__global__ __launch_bounds__(256) void k_refine(const float* __restrict__ feat,
        const float* __restrict__ bank, const int* __restrict__ top,
        const double* __restrict__ binv, short* __restrict__ nf)
{
    __shared__ alignas(16) float qs[64 * 260];
    __shared__ double refv[64][NC];
    __shared__ int    cidx[64][NC];
    __shared__ double qinv[64];
    __shared__ float  wgt[64][5];
    __shared__ int    sel[64][5];
    double* pss = &refv[0][0];   // alias: used before refv is written

    const int t = threadIdx.x;
    const int qbase = blockIdx.x * 64;
    const int q = t >> 2, p = t & 3;

    // stage q rows fp32 + fp64 sumsq
    {
        const float4* src = (const float4*)(feat + (size_t)(qbase + q) * DIM + p * 64);
        float* dst = qs + q * 260 + p * 64;
        double ss = 0.0;
        #pragma unroll
        for (int i = 0; i < 16; ++i) {
            float4 v = src[i];
            dst[i*4+0] = v.x; dst[i*4+1] = v.y; dst[i*4+2] = v.z; dst[i*4+3] = v.w;
            ss += (double)v.x * v.x + (double)v.y * v.y + (double)v.z * v.z + (double)v.w * v.w;
        }
        pss[q * 4 + p] = ss;
    }
    #pragma unroll
    for (int j = 0; j < 3; ++j) {
        int g = t + j * 256;
        cidx[g / NC][g % NC] = top[(size_t)qbase * NC + g];
    }
    __syncthreads();
    if (p == 0) {
        double s = pss[q*4+0] + pss[q*4+1] + pss[q*4+2] + pss[q*4+3];
        double n = sqrt(s); if (n < 1e-12) n = 1e-12;
        qinv[q] = 1.0 / n;
    }
    __syncthreads();

    for (int c = 0; c < 3; ++c) {
        const int ci = cidx[q][p * 3 + c];
        const float4* br = (const float4*)(bank + (size_t)ci * DIM);
        const float4* qr = (const float4*)(qs + q * 260);
        double a0 = 0, a1 = 0, a2 = 0, a3 = 0;
        #pragma unroll 4
        for (int i = 0; i < 64; ++i) {
            float4 a = qr[i]; float4 b = br[i];
            a0 += (double)a.x * b.x; a1 += (double)a.y * b.y;
            a2 += (double)a.z * b.z; a3 += (double)a.w * b.w;
        }
        refv[q][p * 3 + c] = ((a0 + a1) + (a2 + a3)) * qinv[q] * binv[ci];
    }
    __syncthreads();

    if (p == 0) {
        double v[NC]; int id[NC];
        #pragma unroll
        for (int s = 0; s < NC; ++s) { v[s] = refv[q][s]; id[s] = cidx[q][s]; }
        double pv[5]; int pi[5];
        #pragma unroll
        for (int k = 0; k < 5; ++k) {
            double best = -1e300; int bs = 0;
            #pragma unroll
            for (int s = 0; s < NC; ++s) if (v[s] > best) { best = v[s]; bs = s; }
            pv[k] = best;
            #pragma unroll
            for (int s = 0; s < NC; ++s) if (s == bs) { pi[k] = id[s]; v[s] = -1e300; }
        }
        const double m = pv[0];
        float e[5]; float sum = 0.f;
        #pragma unroll
        for (int k = 0; k < 5; ++k) { e[k] = expf((float)(pv[k] - m)); sum += e[k]; }
        const float inv = 1.0f / sum;
        #pragma unroll
        for (int k = 0; k < 5; ++k) { wgt[q][k] = e[k] * inv; sel[q][k] = pi[k]; }
    }
    __syncthreads();

    {
        const float w0 = wgt[q][0], w1 = wgt[q][1], w2 = wgt[q][2], w3 = wgt[q][3], w4 = wgt[q][4];
        const float4* b0 = (const float4*)(bank + (size_t)sel[q][0] * DIM + p * 64);
        const float4* b1 = (const float4*)(bank + (size_t)sel[q][1] * DIM + p * 64);
        const float4* b2 = (const float4*)(bank + (size_t)sel[q][2] * DIM + p * 64);
        const float4* b3 = (const float4*)(bank + (size_t)sel[q][3] * DIM + p * 64);
        const float4* b4 = (const float4*)(bank + (size_t)sel[q][4] * DIM + p * 64);
        short* od = nf + (size_t)(qbase + q) * DIM + p * 64;
        #pragma unroll
        for (int i = 0; i < 16; ++i) {
            float4 x0 = b0[i], x1 = b1[i], x2 = b2[i], x3 = b3[i], x4 = b4[i];
            float ox = w0*x0.x + w1*x1.x + w2*x2.x + w3*x3.x + w4*x4.x;
            float oy = w0*x0.y + w1*x1.y + w2*x2.y + w3*x3.y + w4*x4.y;
            float oz = w0*x0.z + w1*x1.z + w2*x2.z + w3*x3.z + w4*x4.z;
            float ow = w0*x0.w + w1*x1.w + w2*x2.w + w3*x3.w + w4*x4.w;
            uint2 u;
            u.x = ((unsigned)(unsigned short)f32bf(ox)) | (((unsigned)(unsigned short)f32bf(oy)) << 16);
            u.y = ((unsigned)(unsigned short)f32bf(oz)) | (((unsigned)(unsigned short)f32bf(ow)) << 16);
            *(uint2*)(od + i * 4) = u;
        }
    }
}

// --------------------------------------------------------------- MLP 1 ------
// h = relu([feat | nf] @ W1^T + b1) -> bf16. M=65536,N=256,K=512. 128x128 tile.
__global__ __launch_bounds__(256) void k_mlp1(const float* __restrict__ feat,
        const short* __restrict__ nf, const short* __restrict__ w1bf,
        const float* __restrict__ b1, short* __restrict__ h)
{
    __shared__ alignas(16) short As[128 * 40];
    __shared__ alignas(16) short Bs[128 * 40];
    const int t = threadIdx.x, lane = t & 63, w = t >> 6;
    const int mb = (blockIdx.x >> 1) * 128;
    const int nb = (blockIdx.x & 1) * 128;
    const int r = t >> 1, hh = t & 1;
    const int mwb = (w >> 1) * 64, nwb = (w & 1) * 64;
    const f32x4 vzero = {0.f, 0.f, 0.f, 0.f};

    f32x4 acc[4][4];
    #pragma unroll
    for (int a = 0; a < 4; ++a)
        #pragma unroll
        for (int b = 0; b < 4; ++b) acc[a][b] = vzero;

    for (int kc = 0; kc < 16; ++kc) {
        short* ad = As + r * 40 + hh * 16;
        if (kc < 8) {
            const float4* s = (const float4*)(feat + (size_t)(mb + r) * 256 + kc * 32 + hh * 16);
            #pragma unroll
            for (int i = 0; i < 4; ++i) {
                float4 v = s[i];
                ad[i*4+0] = f32bf(v.x); ad[i*4+1] = f32bf(v.y);
                ad[i*4+2] = f32bf(v.z); ad[i*4+3] = f32bf(v.w);
            }
        } else {
            const uint4* s = (const uint4*)(nf + (size_t)(mb + r) * 256 + (kc - 8) * 32 + hh * 16);
            *(uint4*)ad = s[0]; *(uint4*)(ad + 8) = s[1];
        }
        {
            const uint4* bsrc = (const uint4*)(w1bf + (size_t)(nb + r) * 512 + kc * 32 + hh * 16);
            short* bd = Bs + r * 40 + hh * 16;
            *(uint4*)bd = bsrc[0]; *(uint4*)(bd + 8) = bsrc[1];
        }
        __syncthreads();
        short8 af[4], bf[4];
        const int ko = (lane >> 4) << 3;
        #pragma unroll
        for (int mt = 0; mt < 4; ++mt)
            af[mt] = *(const short8*)(As + (mwb + mt * 16 + (lane & 15)) * 40 + ko);
        #pragma unroll
        for (int nt = 0; nt < 4; ++nt)
            bf[nt] = *(const short8*)(Bs + (nwb + nt * 16 + (lane & 15)) * 40 + ko);
        #pragma unroll
        for (int mt = 0; mt < 4; ++mt)
            #pragma unroll
            for (int nt = 0; nt < 4; ++nt)
                acc[mt][nt] = __builtin_amdgcn_mfma_f32_16x16x32_bf16(af[mt], bf[nt], acc[mt][nt], 0, 0, 0);
        __syncthreads();
    }
    // epilogue: bias + relu -> bf16
    {
        const int rq = (lane >> 4) << 2;
        const int cc = lane & 15;
        #pragma unroll
        for (int mt = 0; mt < 4; ++mt)
            #pragma unroll
            for (int nt = 0; nt < 4; ++nt) {
                const int row = mb + mwb + mt * 16 + rq;
                const int col = nb + nwb + nt * 16 + cc;
                const float bias = b1[col];
                #pragma unroll
                for (int rr = 0; rr < 4; ++rr) {
                    float v = acc[mt][nt][rr] + bias;
                    v = fmaxf(v, 0.f);
                    h[(size_t)(row + rr) * 256 + col] = f32bf(v);
                }
            }
    }
}

// --------------------------------------------------------------- MLP 2 ------
// out = h @ W2^T + b2 (fp32). M=65536,N=256,K=256.
__global__ __launch_bounds__(256) void k_mlp2(const short* __restrict__ h,
        const short* __restrict__ w2bf, const float* __restrict__ b2,
        float* __restrict__ out)
{
    __shared__ alignas(16) short As[128 * 40];
    __shared__ alignas(16) short Bs[128 * 40];
    const int t = threadIdx.x, lane = t & 63, w = t >> 6;
    const int mb = (blockIdx.x >> 1) * 128;
    const int nb = (blockIdx.x & 1) * 128;
    const int r = t >> 1, hh = t & 1;
    const int mwb = (w >> 1) * 64, nwb = (w & 1) * 64;
    const f32x4 vzero = {0.f, 0.f, 0.f, 0.f};

    f32x4 acc[4][4];
    #pragma unroll
    for (int a = 0; a < 4; ++a)
        #pragma unroll
        for (int b = 0; b < 4; ++b) acc[a][b] = vzero;

    for (int kc = 0; kc < 8; ++kc) {
        {
            const uint4* s = (const uint4*)(h + (size_t)(mb + r) * 256 + kc * 32 + hh * 16);
            short* ad = As + r * 40 + hh * 16;
            *(uint4*)ad = s[0]; *(uint4*)(ad + 8) = s[1];
        }
        {
            const uint4* bsrc = (const uint4*)(w2bf + (size_t)(nb + r) * 256 + kc * 32 + hh * 16);
            short* bd = Bs + r * 40 + hh * 16;
            *(uint4*)bd = bsrc[0]; *(uint4*)(bd + 8) = bsrc[1];
        }
        __syncthreads();
        short8 af[4], bf[4];
        const int ko = (lane >> 4) << 3;
        #pragma unroll
        for (int mt = 0; mt < 4; ++mt)
            af[mt] = *(const short8*)(As + (mwb + mt * 16 + (lane & 15)) * 40 + ko);
        #pragma unroll
        for (int nt = 0; nt < 4; ++nt)
            bf[nt] = *(const short8*)(Bs + (nwb + nt * 16 + (lane & 15)) * 40 + ko);
        #pragma unroll
        for (int mt = 0; mt < 4; ++mt)
            #pragma unroll
            for (int nt = 0; nt < 4; ++nt)
                acc[mt][nt] = __builtin_amdgcn_mfma_f32_16x16x32_bf16(af[mt], bf[nt], acc[mt][nt], 0, 0, 0);
        __syncthreads();
    }
    {
        const int rq = (lane >> 4) << 2;
        const int cc = lane & 15;
        #pragma unroll
        for (int mt = 0; mt < 4; ++mt)
            #pragma unroll
            for (int nt = 0; nt < 4; ++nt) {
                const int row = mb + mwb + mt * 16 + rq;
                const int col = nb + nwb + nt * 16 + cc;
                const float bias = b2[col];
                #pragma unroll
                for (int rr = 0; rr < 4; ++rr)
                    out[(size_t)(row + rr) * 256 + col] = acc[mt][nt][rr] + bias;
            }
    }
}

// ------------------------------------------------------------- launcher -----
extern "C" void kernel_launch(void* const* d_in, const int* in_sizes, int n_in,
                              void* d_out, int out_size, void* d_ws, size_t ws_size,
                              hipStream_t stream) {
    const float* feat = (const float*)d_in[0];
    const float* bank = (const float*)d_in[1];
    const float* W1   = (const float*)d_in[2];
    const float* b1   = (const float*)d_in[3];
    const float* W2   = (const float*)d_in[4];
    const float* b2   = (const float*)d_in[5];
    float* out = (float*)d_out;

    char* ws = (char*)d_ws;
    short*  bnbf = (short*)(ws + 0);              // 1024*256*2   = 524288
    double* binv = (double*)(ws + 524288);        // 1024*8       = 8192
    short*  w1bf = (short*)(ws + 532480);         // 131072*2     = 262144
    short*  w2bf = (short*)(ws + 794624);         // 65536*2      = 131072
    int*    top  = (int*)(ws + 925696);           // 65536*12*4   = 3145728
    short*  nf   = (short*)(ws + 4071424);        // 65536*256*2  = 33554432
    short*  hbuf = (short*)(ws + 37625856);       // 65536*256*2  = 33554432
    // total 71180288 bytes

    k_prep  <<<1792, 256, 0, stream>>>(bank, W1, W2, bnbf, binv, w1bf, w2bf);
    k_presel<<<1024, 256, 0, stream>>>(feat, bnbf, top);
    k_refine<<<1024, 256, 0, stream>>>(feat, bank, top, binv, nf);
    k_mlp1  <<<1024, 256, 0, stream>>>(feat, nf, w1bf, b1, hbuf);
    k_mlp2  <<<1024, 256, 0, stream>>>(hbuf, w2bf, b2, out);
}

// Round 2
// 514.183 us; speedup vs baseline: 1.1101x; 1.1101x over previous
//
#include <hip/hip_runtime.h>

#define DIM 256
#define NC 12

typedef __attribute__((ext_vector_type(8))) short short8;
typedef __attribute__((ext_vector_type(4))) float f32x4;

__device__ __forceinline__ short f32bf(float f) {
    unsigned u = __builtin_bit_cast(unsigned, f);
    unsigned r = u + 0x7FFFu + ((u >> 16) & 1u);
    return (short)(r >> 16);
}

__device__ __forceinline__ void gld_lds16(const void* g, void* l) {
    __builtin_amdgcn_global_load_lds((const __attribute__((address_space(1))) unsigned int*)g,
                                     (__attribute__((address_space(3))) unsigned int*)l, 16, 0, 0);
}

template<int CTRL>
__device__ __forceinline__ unsigned dppmax(unsigned x) {
    unsigned y = (unsigned)__builtin_amdgcn_update_dpp(0, (int)x, CTRL, 0xF, 0xF, true);
    return x > y ? x : y;
}

// ---------------------------------------------------------------- prep ------
// blocks 0..1023   : bank fp64 norms + normalized bf16 bank, 16B-block SWIZZLED
//                    layout (phys_kb = kb ^ (row&7)) so global_load_lds's linear
//                    LDS image gives conflict-free A-fragment reads in k_sims.
// blocks 1024..1535: W1 -> bf16;  1536..1791: W2 -> bf16
__global__ __launch_bounds__(256) void k_prep(const float* __restrict__ bank,
        const float* __restrict__ W1, const float* __restrict__ W2,
        short* __restrict__ bnbf, double* __restrict__ binv,
        short* __restrict__ w1bf, short* __restrict__ w2bf)
{
    __shared__ double part[4];
    __shared__ double s_inv;
    const int bid = blockIdx.x, t = threadIdx.x;
    if (bid < 1024) {
        const int row = bid;
        if (row < 1000) {
            float v = bank[(size_t)row * DIM + t];
            double ssq = (double)v * (double)v;
            for (int o = 32; o > 0; o >>= 1) ssq += __shfl_down(ssq, o);
            if ((t & 63) == 0) part[t >> 6] = ssq;
            __syncthreads();
            if (t == 0) {
                double s = part[0] + part[1] + part[2] + part[3];
                double n = sqrt(s); if (n < 1e-12) n = 1e-12;
                double inv = 1.0 / n;
                binv[row] = inv; s_inv = inv;
            }
            __syncthreads();
            const int pcol = (((t >> 3) ^ (row & 7)) << 3) | (t & 7);
            bnbf[(size_t)row * DIM + pcol] = f32bf((float)((double)v * s_inv));
        } else {
            bnbf[(size_t)row * DIM + t] = 0;
            if (t == 0) binv[row] = 0.0;
        }
    } else if (bid < 1536) {
        const int i = (bid - 1024) * 256 + t;
        w1bf[i] = f32bf(W1[i]);
    } else {
        const int i = (bid - 1536) * 256 + t;
        w2bf[i] = f32bf(W2[i]);
    }
}

// ---------------------------------------------------------------- sims ------
// sims[q][bank] bf16 for one slice of 16384 queries. Block = 64 queries x all
// 1024 banks, K=256. Query (B-op) frags cached in 32 VGPR-short8s; bank (A-op)
// chunks of 64 rows staged via global_load_lds (swizzled source). Per k-step:
// 1 ds_read_b128 + 4 MFMA.
__global__ __launch_bounds__(256) void k_sims(const float* __restrict__ feat,
        const short* __restrict__ bnbf, short* __restrict__ sims, int qoff)
{
    __shared__ alignas(16) short Qs[64 * 264];
    __shared__ alignas(16) short Ab[64 * 256];
    const int t = threadIdx.x, lane = t & 63, w = t >> 6;
    const int n16 = lane & 15, q4 = lane >> 4;

    // stage queries -> bf16 LDS (padded ld=264)
    {
        const int r = t >> 2, p = t & 3;
        const float4* src = (const float4*)(feat + (size_t)(qoff + blockIdx.x * 64 + r) * DIM + p * 64);
        short* dst = Qs + r * 264 + p * 64;
        #pragma unroll
        for (int i = 0; i < 16; ++i) {
            float4 v = src[i];
            dst[i*4+0] = f32bf(v.x); dst[i*4+1] = f32bf(v.y);
            dst[i*4+2] = f32bf(v.z); dst[i*4+3] = f32bf(v.w);
        }
    }
    const char* gA = (const char*)bnbf;
    char* lA = (char*)Ab;
    #pragma unroll
    for (int i = 0; i < 8; ++i)
        gld_lds16(gA + i * 4096 + t * 16, lA + i * 4096 + (t >> 6) * 1024);
    __syncthreads();

    // cache all B (query) fragments in registers: bq[kc][nt]
    short8 bq[8][4];
    #pragma unroll
    for (int kc = 0; kc < 8; ++kc)
        #pragma unroll
        for (int nt = 0; nt < 4; ++nt)
            bq[kc][nt] = *(const short8*)(Qs + (nt * 16 + n16) * 264 + kc * 32 + q4 * 8);

    // A-frag LDS byte offsets (swizzled; constant across chunks)
    const int ml = w * 16 + n16;              // chunk-local bank row
    int aoff[8];
    #pragma unroll
    for (int kc = 0; kc < 8; ++kc)
        aoff[kc] = (ml * 256 + (((kc * 4 + q4) ^ (ml & 7)) << 3)) * 2;

    const f32x4 vzero = {0.f, 0.f, 0.f, 0.f};
    for (int chunk = 0; chunk < 16; ++chunk) {
        f32x4 acc[4];
        acc[0] = vzero; acc[1] = vzero; acc[2] = vzero; acc[3] = vzero;
        #pragma unroll
        for (int kc = 0; kc < 8; ++kc) {
            short8 af = *(const short8*)(lA + aoff[kc]);
            #pragma unroll
            for (int nt = 0; nt < 4; ++nt)
                acc[nt] = __builtin_amdgcn_mfma_f32_16x16x32_bf16(af, bq[kc][nt], acc[nt], 0, 0, 0);
        }
        // epilogue: 4 consecutive banks per lane -> bf16x4 (8B) store
        const int bankb = chunk * 64 + w * 16 + q4 * 4;
        #pragma unroll
        for (int nt = 0; nt < 4; ++nt) {
            const int qc = blockIdx.x * 64 + nt * 16 + n16;
            uint2 u;
            u.x = ((unsigned)(unsigned short)f32bf(acc[nt][0])) |
                  (((unsigned)(unsigned short)f32bf(acc[nt][1])) << 16);
            u.y = ((unsigned)(unsigned short)f32bf(acc[nt][2])) |
                  (((unsigned)(unsigned short)f32bf(acc[nt][3])) << 16);
            *(uint2*)(sims + (size_t)qc * 1024 + bankb) = u;
        }
        __syncthreads();                       // all waves done reading Ab
        if (chunk < 15) {
            #pragma unroll
            for (int i = 0; i < 8; ++i)
                gld_lds16(gA + (size_t)(chunk + 1) * 32768 + i * 4096 + t * 16,
                          lA + i * 4096 + (t >> 6) * 1024);
            __syncthreads();                   // staging complete
        }
    }
}

// -------------------------------------------------------------- select ------
// Exact bf16 top-12 per query. One wave per query: 16 keys/lane
// (mono-u16<<16 | bank), unrolled bitonic sort (descending), then 12
// DPP-max-reduce extraction rounds with O(1) shift refill. No divergent
// serial inserts, no LDS.
__global__ __launch_bounds__(256) void k_select(const short* __restrict__ sims,
        int* __restrict__ top, int qoff)
{
    const int t = threadIdx.x, lane = t & 63, w = t >> 6;
    const int q = blockIdx.x * 4 + w;          // slice-local query
    const uint4* p = (const uint4*)(sims + (size_t)q * 1024 + lane * 16);
    uint4 a = p[0], b = p[1];

    unsigned k[16];
    {
        unsigned words[8] = {a.x, a.y, a.z, a.w, b.x, b.y, b.z, b.w};
        #pragma unroll
        for (int j = 0; j < 16; ++j) {
            unsigned h = (j & 1) ? (words[j >> 1] >> 16) : (words[j >> 1] & 0xFFFFu);
            unsigned m = (h ^ 0x8000u) ^ ((0u - (h >> 15)) & 0x7FFFu);  // monotone u16
            int idx = lane * 16 + j;
            k[j] = (idx < 1000) ? ((m << 16) | (unsigned)idx) : 0u;
        }
    }
    // bitonic sort, descending
    #pragma unroll
    for (int sz = 2; sz <= 16; sz <<= 1)
        #pragma unroll
        for (int st = sz >> 1; st >= 1; st >>= 1)
            #pragma unroll
            for (int i = 0; i < 16; ++i) {
                int j = i ^ st;
                if (j > i) {
                    bool desc = ((i & sz) == 0);
                    unsigned lo = k[i], hi = k[j];
                    unsigned mx = lo > hi ? lo : hi;
                    unsigned mn = lo > hi ? hi : lo;
                    k[i] = desc ? mx : mn;
                    k[j] = desc ? mn : mx;
                }
            }
    unsigned mine = 0;
    #pragma unroll
    for (int r = 0; r < 12; ++r) {
        unsigned m = k[0];
        m = dppmax<0xB1>(m);   // quad_perm xor1
        m = dppmax<0x4E>(m);   // quad_perm xor2
        m = dppmax<0x141>(m);  // row_half_mirror
        m = dppmax<0x140>(m);  // row_mirror
        m = dppmax<0x142>(m);  // row_bcast15
        m = dppmax<0x143>(m);  // row_bcast31
        unsigned wm = (unsigned)__builtin_amdgcn_readlane((int)m, 63);
        if (lane == r) mine = wm;
        if (k[0] == wm) {
            #pragma unroll
            for (int s = 0; s < 12; ++s) k[s] = k[s + 1];
        }
    }
    if (lane < 12) top[(size_t)(qoff + q) * NC + lane] = (int)(mine & 0xFFFFu);
}

// -------------------------------------------------------------- refine ------
// fp64 re-computation of the 12 candidate cosine sims, exact top-5, softmax,
// nf = sum w_k * bank_row_k  -> bf16. 64 queries/block, 4 threads/query.
__global__ __launch_bounds__(256) void k_refine(const float* __restrict__ feat,
        const float* __restrict__ bank, const int* __restrict__ top,
        const double* __restrict__ binv, short* __restrict__ nf)
{
    __shared__ alignas(16) float qs[64 * 260];
    __shared__ double refv[64][NC];
    __shared__ int    cidx[64][NC];
    __shared__ double qinv[64];
    __shared__ float  wgt[64][5];
    __shared__ int    sel[64][5];
    double* pss = &refv[0][0];   // alias: used before refv is written

    const int t = threadIdx.x;
    const int qbase = blockIdx.x * 64;
    const int q = t >> 2, p = t & 3;

    {
        const float4* src = (const float4*)(feat + (size_t)(qbase + q) * DIM + p * 64);
        float* dst = qs + q * 260 + p * 64;
        double ss = 0.0;
        #pragma unroll
        for (int i = 0; i < 16; ++i) {
            float4 v = src[i];
            dst[i*4+0] = v.x; dst[i*4+1] = v.y; dst[i*4+2] = v.z; dst[i*4+3] = v.w;
            ss += (double)v.x * v.x + (double)v.y * v.y + (double)v.z * v.z + (double)v.w * v.w;
        }
        pss[q * 4 + p] = ss;
    }
    #pragma unroll
    for (int j = 0; j < 3; ++j) {
        int g = t + j * 256;
        cidx[g / NC][g % NC] = top[(size_t)qbase * NC + g];
    }
    __syncthreads();
    if (p == 0) {
        double s = pss[q*4+0] + pss[q*4+1] + pss[q*4+2] + pss[q*4+3];
        double n = sqrt(s); if (n < 1e-12) n = 1e-12;
        qinv[q] = 1.0 / n;
    }
    __syncthreads();

    for (int c = 0; c < 3; ++c) {
        const int ci = cidx[q][p * 3 + c];
        const float4* br = (const float4*)(bank + (size_t)ci * DIM);
        const float4* qr = (const float4*)(qs + q * 260);
        double a0 = 0, a1 = 0, a2 = 0, a3 = 0;
        #pragma unroll 4
        for (int i = 0; i < 64; ++i) {
            float4 a = qr[i]; float4 b = br[i];
            a0 += (double)a.x * b.x; a1 += (double)a.y * b.y;
            a2 += (double)a.z * b.z; a3 += (double)a.w * b.w;
        }
        refv[q][p * 3 + c] = ((a0 + a1) + (a2 + a3)) * qinv[q] * binv[ci];
    }
    __syncthreads();

    if (p == 0) {
        double v[NC]; int id[NC];
        #pragma unroll
        for (int s = 0; s < NC; ++s) { v[s] = refv[q][s]; id[s] = cidx[q][s]; }
        double pv[5]; int pi[5];
        #pragma unroll
        for (int kk = 0; kk < 5; ++kk) {
            double best = -1e300; int bs = 0;
            #pragma unroll
            for (int s = 0; s < NC; ++s) if (v[s] > best) { best = v[s]; bs = s; }
            pv[kk] = best;
            #pragma unroll
            for (int s = 0; s < NC; ++s) if (s == bs) { pi[kk] = id[s]; v[s] = -1e300; }
        }
        const double m = pv[0];
        float e[5]; float sum = 0.f;
        #pragma unroll
        for (int kk = 0; kk < 5; ++kk) { e[kk] = expf((float)(pv[kk] - m)); sum += e[kk]; }
        const float inv = 1.0f / sum;
        #pragma unroll
        for (int kk = 0; kk < 5; ++kk) { wgt[q][kk] = e[kk] * inv; sel[q][kk] = pi[kk]; }
    }
    __syncthreads();

    {
        const float w0 = wgt[q][0], w1 = wgt[q][1], w2 = wgt[q][2], w3 = wgt[q][3], w4 = wgt[q][4];
        const float4* b0 = (const float4*)(bank + (size_t)sel[q][0] * DIM + p * 64);
        const float4* b1 = (const float4*)(bank + (size_t)sel[q][1] * DIM + p * 64);
        const float4* b2 = (const float4*)(bank + (size_t)sel[q][2] * DIM + p * 64);
        const float4* b3 = (const float4*)(bank + (size_t)sel[q][3] * DIM + p * 64);
        const float4* b4 = (const float4*)(bank + (size_t)sel[q][4] * DIM + p * 64);
        short* od = nf + (size_t)(qbase + q) * DIM + p * 64;
        #pragma unroll
        for (int i = 0; i < 16; ++i) {
            float4 x0 = b0[i], x1 = b1[i], x2 = b2[i], x3 = b3[i], x4 = b4[i];
            float ox = w0*x0.x + w1*x1.x + w2*x2.x + w3*x3.x + w4*x4.x;
            float oy = w0*x0.y + w1*x1.y + w2*x2.y + w3*x3.y + w4*x4.y;
            float oz = w0*x0.z + w1*x1.z + w2*x2.z + w3*x3.z + w4*x4.z;
            float ow = w0*x0.w + w1*x1.w + w2*x2.w + w3*x3.w + w4*x4.w;
            uint2 u;
            u.x = ((unsigned)(unsigned short)f32bf(ox)) | (((unsigned)(unsigned short)f32bf(oy)) << 16);
            u.y = ((unsigned)(unsigned short)f32bf(oz)) | (((unsigned)(unsigned short)f32bf(ow)) << 16);
            *(uint2*)(od + i * 4) = u;
        }
    }
}

// --------------------------------------------------------------- MLP 1 ------
__global__ __launch_bounds__(256) void k_mlp1(const float* __restrict__ feat,
        const short* __restrict__ nf, const short* __restrict__ w1bf,
        const float* __restrict__ b1, short* __restrict__ h)
{
    __shared__ alignas(16) short As[128 * 40];
    __shared__ alignas(16) short Bs[128 * 40];
    const int t = threadIdx.x, lane = t & 63, w = t >> 6;
    const int mb = (blockIdx.x >> 1) * 128;
    const int nb = (blockIdx.x & 1) * 128;
    const int r = t >> 1, hh = t & 1;
    const int mwb = (w >> 1) * 64, nwb = (w & 1) * 64;
    const f32x4 vzero = {0.f, 0.f, 0.f, 0.f};

    f32x4 acc[4][4];
    #pragma unroll
    for (int a = 0; a < 4; ++a)
        #pragma unroll
        for (int b = 0; b < 4; ++b) acc[a][b] = vzero;

    for (int kc = 0; kc < 16; ++kc) {
        short* ad = As + r * 40 + hh * 16;
        if (kc < 8) {
            const float4* s = (const float4*)(feat + (size_t)(mb + r) * 256 + kc * 32 + hh * 16);
            #pragma unroll
            for (int i = 0; i < 4; ++i) {
                float4 v = s[i];
                ad[i*4+0] = f32bf(v.x); ad[i*4+1] = f32bf(v.y);
                ad[i*4+2] = f32bf(v.z); ad[i*4+3] = f32bf(v.w);
            }
        } else {
            const uint4* s = (const uint4*)(nf + (size_t)(mb + r) * 256 + (kc - 8) * 32 + hh * 16);
            *(uint4*)ad = s[0]; *(uint4*)(ad + 8) = s[1];
        }
        {
            const uint4* bsrc = (const uint4*)(w1bf + (size_t)(nb + r) * 512 + kc * 32 + hh * 16);
            short* bd = Bs + r * 40 + hh * 16;
            *(uint4*)bd = bsrc[0]; *(uint4*)(bd + 8) = bsrc[1];
        }
        __syncthreads();
        short8 af[4], bf[4];
        const int ko = (lane >> 4) << 3;
        #pragma unroll
        for (int mt = 0; mt < 4; ++mt)
            af[mt] = *(const short8*)(As + (mwb + mt * 16 + (lane & 15)) * 40 + ko);
        #pragma unroll
        for (int nt = 0; nt < 4; ++nt)
            bf[nt] = *(const short8*)(Bs + (nwb + nt * 16 + (lane & 15)) * 40 + ko);
        #pragma unroll
        for (int mt = 0; mt < 4; ++mt)
            #pragma unroll
            for (int nt = 0; nt < 4; ++nt)
                acc[mt][nt] = __builtin_amdgcn_mfma_f32_16x16x32_bf16(af[mt], bf[nt], acc[mt][nt], 0, 0, 0);
        __syncthreads();
    }
    {
        const int rq = (lane >> 4) << 2;
        const int cc = lane & 15;
        #pragma unroll
        for (int mt = 0; mt < 4; ++mt)
            #pragma unroll
            for (int nt = 0; nt < 4; ++nt) {
                const int row = mb + mwb + mt * 16 + rq;
                const int col = nb + nwb + nt * 16 + cc;
                const float bias = b1[col];
                #pragma unroll
                for (int rr = 0; rr < 4; ++rr) {
                    float v = acc[mt][nt][rr] + bias;
                    v = fmaxf(v, 0.f);
                    h[(size_t)(row + rr) * 256 + col] = f32bf(v);
                }
            }
    }
}

// --------------------------------------------------------------- MLP 2 ------
__global__ __launch_bounds__(256) void k_mlp2(const short* __restrict__ h,
        const short* __restrict__ w2bf, const float* __restrict__ b2,
        float* __restrict__ out)
{
    __shared__ alignas(16) short As[128 * 40];
    __shared__ alignas(16) short Bs[128 * 40];
    const int t = threadIdx.x, lane = t & 63, w = t >> 6;
    const int mb = (blockIdx.x >> 1) * 128;
    const int nb = (blockIdx.x & 1) * 128;
    const int r = t >> 1, hh = t & 1;
    const int mwb = (w >> 1) * 64, nwb = (w & 1) * 64;
    const f32x4 vzero = {0.f, 0.f, 0.f, 0.f};

    f32x4 acc[4][4];
    #pragma unroll
    for (int a = 0; a < 4; ++a)
        #pragma unroll
        for (int b = 0; b < 4; ++b) acc[a][b] = vzero;

    for (int kc = 0; kc < 8; ++kc) {
        {
            const uint4* s = (const uint4*)(h + (size_t)(mb + r) * 256 + kc * 32 + hh * 16);
            short* ad = As + r * 40 + hh * 16;
            *(uint4*)ad = s[0]; *(uint4*)(ad + 8) = s[1];
        }
        {
            const uint4* bsrc = (const uint4*)(w2bf + (size_t)(nb + r) * 256 + kc * 32 + hh * 16);
            short* bd = Bs + r * 40 + hh * 16;
            *(uint4*)bd = bsrc[0]; *(uint4*)(bd + 8) = bsrc[1];
        }
        __syncthreads();
        short8 af[4], bf[4];
        const int ko = (lane >> 4) << 3;
        #pragma unroll
        for (int mt = 0; mt < 4; ++mt)
            af[mt] = *(const short8*)(As + (mwb + mt * 16 + (lane & 15)) * 40 + ko);
        #pragma unroll
        for (int nt = 0; nt < 4; ++nt)
            bf[nt] = *(const short8*)(Bs + (nwb + nt * 16 + (lane & 15)) * 40 + ko);
        #pragma unroll
        for (int mt = 0; mt < 4; ++mt)
            #pragma unroll
            for (int nt = 0; nt < 4; ++nt)
                acc[mt][nt] = __builtin_amdgcn_mfma_f32_16x16x32_bf16(af[mt], bf[nt], acc[mt][nt], 0, 0, 0);
        __syncthreads();
    }
    {
        const int rq = (lane >> 4) << 2;
        const int cc = lane & 15;
        #pragma unroll
        for (int mt = 0; mt < 4; ++mt)
            #pragma unroll
            for (int nt = 0; nt < 4; ++nt) {
                const int row = mb + mwb + mt * 16 + rq;
                const int col = nb + nwb + nt * 16 + cc;
                const float bias = b2[col];
                #pragma unroll
                for (int rr = 0; rr < 4; ++rr)
                    out[(size_t)(row + rr) * 256 + col] = acc[mt][nt][rr] + bias;
            }
    }
}

// ------------------------------------------------------------- launcher -----
extern "C" void kernel_launch(void* const* d_in, const int* in_sizes, int n_in,
                              void* d_out, int out_size, void* d_ws, size_t ws_size,
                              hipStream_t stream) {
    const float* feat = (const float*)d_in[0];
    const float* bank = (const float*)d_in[1];
    const float* W1   = (const float*)d_in[2];
    const float* b1   = (const float*)d_in[3];
    const float* W2   = (const float*)d_in[4];
    const float* b2   = (const float*)d_in[5];
    float* out = (float*)d_out;

    char* ws = (char*)d_ws;
    short*  bnbf = (short*)(ws + 0);              // 1024*256*2   = 524288
    double* binv = (double*)(ws + 524288);        // 1024*8       = 8192
    short*  w1bf = (short*)(ws + 532480);         // 131072*2     = 262144
    short*  w2bf = (short*)(ws + 794624);         // 65536*2      = 131072
    int*    top  = (int*)(ws + 925696);           // 65536*12*4   = 3145728
    short*  nf   = (short*)(ws + 4071424);        // 65536*256*2  = 33554432
    short*  X    = (short*)(ws + 37625856);       // 33554432: sims slices, then h
    // total 71180288 bytes (same as round-1 known-good)

    k_prep<<<1792, 256, 0, stream>>>(bank, W1, W2, bnbf, binv, w1bf, w2bf);
    for (int s = 0; s < 4; ++s) {
        const int qoff = s * 16384;
        k_sims  <<<256,  256, 0, stream>>>(feat, bnbf, X, qoff);
        k_select<<<4096, 256, 0, stream>>>(X, top, qoff);
    }
    k_refine<<<1024, 256, 0, stream>>>(feat, bank, top, binv, nf);
    k_mlp1  <<<1024, 256, 0, stream>>>(feat, nf, w1bf, b1, (short*)X);
    k_mlp2  <<<1024, 256, 0, stream>>>((short*)X, w2bf, b2, out);
}

// Round 3
// 433.858 us; speedup vs baseline: 1.3156x; 1.1851x over previous
//
#include <hip/hip_runtime.h>

#define DIM 256
#define NC 12

typedef __attribute__((ext_vector_type(8))) short short8;
typedef __attribute__((ext_vector_type(4))) float f32x4;

__device__ __forceinline__ short f32bf(float f) {
    unsigned u = __builtin_bit_cast(unsigned, f);
    unsigned r = u + 0x7FFFu + ((u >> 16) & 1u);
    return (short)(r >> 16);
}

__device__ __forceinline__ void gld_lds16(const void* g, void* l) {
    __builtin_amdgcn_global_load_lds((const __attribute__((address_space(1))) unsigned int*)g,
                                     (__attribute__((address_space(3))) unsigned int*)l, 16, 0, 0);
}

template<int CTRL>
__device__ __forceinline__ unsigned dppmax(unsigned x) {
    unsigned y = (unsigned)__builtin_amdgcn_update_dpp(0, (int)x, CTRL, 0xF, 0xF, true);
    return x > y ? x : y;
}

// ---------------------------------------------------------------- prep ------
// blocks 0..1023   : bank fp64 norms + normalized bf16 bank, 16B-block SWIZZLED
//                    layout (phys_kb = kb ^ (row&7)) so global_load_lds's linear
//                    LDS image gives conflict-free A-fragment reads in k_sims.
// blocks 1024..1535: W1 -> bf16;  1536..1791: W2 -> bf16
__global__ __launch_bounds__(256) void k_prep(const float* __restrict__ bank,
        const float* __restrict__ W1, const float* __restrict__ W2,
        short* __restrict__ bnbf, double* __restrict__ binv,
        short* __restrict__ w1bf, short* __restrict__ w2bf)
{
    __shared__ double part[4];
    __shared__ double s_inv;
    const int bid = blockIdx.x, t = threadIdx.x;
    if (bid < 1024) {
        const int row = bid;
        if (row < 1000) {
            float v = bank[(size_t)row * DIM + t];
            double ssq = (double)v * (double)v;
            for (int o = 32; o > 0; o >>= 1) ssq += __shfl_down(ssq, o);
            if ((t & 63) == 0) part[t >> 6] = ssq;
            __syncthreads();
            if (t == 0) {
                double s = part[0] + part[1] + part[2] + part[3];
                double n = sqrt(s); if (n < 1e-12) n = 1e-12;
                double inv = 1.0 / n;
                binv[row] = inv; s_inv = inv;
            }
            __syncthreads();
            const int pcol = (((t >> 3) ^ (row & 7)) << 3) | (t & 7);
            bnbf[(size_t)row * DIM + pcol] = f32bf((float)((double)v * s_inv));
        } else {
            bnbf[(size_t)row * DIM + t] = 0;
            if (t == 0) binv[row] = 0.0;
        }
    } else if (bid < 1536) {
        const int i = (bid - 1024) * 256 + t;
        w1bf[i] = f32bf(W1[i]);
    } else {
        const int i = (bid - 1536) * 256 + t;
        w2bf[i] = f32bf(W2[i]);
    }
}

// ---------------------------------------------------------------- sims ------
__global__ __launch_bounds__(256) void k_sims(const float* __restrict__ feat,
        const short* __restrict__ bnbf, short* __restrict__ sims, int qoff)
{
    __shared__ alignas(16) short Qs[64 * 264];
    __shared__ alignas(16) short Ab[64 * 256];
    const int t = threadIdx.x, lane = t & 63, w = t >> 6;
    const int n16 = lane & 15, q4 = lane >> 4;

    {
        const int r = t >> 2, p = t & 3;
        const float4* src = (const float4*)(feat + (size_t)(qoff + blockIdx.x * 64 + r) * DIM + p * 64);
        short* dst = Qs + r * 264 + p * 64;
        #pragma unroll
        for (int i = 0; i < 16; ++i) {
            float4 v = src[i];
            dst[i*4+0] = f32bf(v.x); dst[i*4+1] = f32bf(v.y);
            dst[i*4+2] = f32bf(v.z); dst[i*4+3] = f32bf(v.w);
        }
    }
    const char* gA = (const char*)bnbf;
    char* lA = (char*)Ab;
    #pragma unroll
    for (int i = 0; i < 8; ++i)
        gld_lds16(gA + i * 4096 + t * 16, lA + i * 4096 + (t >> 6) * 1024);
    __syncthreads();

    short8 bq[8][4];
    #pragma unroll
    for (int kc = 0; kc < 8; ++kc)
        #pragma unroll
        for (int nt = 0; nt < 4; ++nt)
            bq[kc][nt] = *(const short8*)(Qs + (nt * 16 + n16) * 264 + kc * 32 + q4 * 8);

    const int ml = w * 16 + n16;
    int aoff[8];
    #pragma unroll
    for (int kc = 0; kc < 8; ++kc)
        aoff[kc] = (ml * 256 + (((kc * 4 + q4) ^ (ml & 7)) << 3)) * 2;

    const f32x4 vzero = {0.f, 0.f, 0.f, 0.f};
    for (int chunk = 0; chunk < 16; ++chunk) {
        f32x4 acc[4];
        acc[0] = vzero; acc[1] = vzero; acc[2] = vzero; acc[3] = vzero;
        #pragma unroll
        for (int kc = 0; kc < 8; ++kc) {
            short8 af = *(const short8*)(lA + aoff[kc]);
            #pragma unroll
            for (int nt = 0; nt < 4; ++nt)
                acc[nt] = __builtin_amdgcn_mfma_f32_16x16x32_bf16(af, bq[kc][nt], acc[nt], 0, 0, 0);
        }
        const int bankb = chunk * 64 + w * 16 + q4 * 4;
        #pragma unroll
        for (int nt = 0; nt < 4; ++nt) {
            const int qc = blockIdx.x * 64 + nt * 16 + n16;
            uint2 u;
            u.x = ((unsigned)(unsigned short)f32bf(acc[nt][0])) |
                  (((unsigned)(unsigned short)f32bf(acc[nt][1])) << 16);
            u.y = ((unsigned)(unsigned short)f32bf(acc[nt][2])) |
                  (((unsigned)(unsigned short)f32bf(acc[nt][3])) << 16);
            *(uint2*)(sims + (size_t)qc * 1024 + bankb) = u;
        }
        __syncthreads();
        if (chunk < 15) {
            #pragma unroll
            for (int i = 0; i < 8; ++i)
                gld_lds16(gA + (size_t)(chunk + 1) * 32768 + i * 4096 + t * 16,
                          lA + i * 4096 + (t >> 6) * 1024);
            __syncthreads();
        }
    }
}

// -------------------------------------------------------------- select ------
__global__ __launch_bounds__(256) void k_select(const short* __restrict__ sims,
        int* __restrict__ top, int qoff)
{
    const int t = threadIdx.x, lane = t & 63, w = t >> 6;
    const int q = blockIdx.x * 4 + w;
    const uint4* p = (const uint4*)(sims + (size_t)q * 1024 + lane * 16);
    uint4 a = p[0], b = p[1];

    unsigned k[16];
    {
        unsigned words[8] = {a.x, a.y, a.z, a.w, b.x, b.y, b.z, b.w};
        #pragma unroll
        for (int j = 0; j < 16; ++j) {
            unsigned h = (j & 1) ? (words[j >> 1] >> 16) : (words[j >> 1] & 0xFFFFu);
            unsigned m = (h ^ 0x8000u) ^ ((0u - (h >> 15)) & 0x7FFFu);
            int idx = lane * 16 + j;
            k[j] = (idx < 1000) ? ((m << 16) | (unsigned)idx) : 0u;
        }
    }
    #pragma unroll
    for (int sz = 2; sz <= 16; sz <<= 1)
        #pragma unroll
        for (int st = sz >> 1; st >= 1; st >>= 1)
            #pragma unroll
            for (int i = 0; i < 16; ++i) {
                int j = i ^ st;
                if (j > i) {
                    bool desc = ((i & sz) == 0);
                    unsigned lo = k[i], hi = k[j];
                    unsigned mx = lo > hi ? lo : hi;
                    unsigned mn = lo > hi ? hi : lo;
                    k[i] = desc ? mx : mn;
                    k[j] = desc ? mn : mx;
                }
            }
    unsigned mine = 0;
    #pragma unroll
    for (int r = 0; r < 12; ++r) {
        unsigned m = k[0];
        m = dppmax<0xB1>(m);
        m = dppmax<0x4E>(m);
        m = dppmax<0x141>(m);
        m = dppmax<0x140>(m);
        m = dppmax<0x142>(m);
        m = dppmax<0x143>(m);
        unsigned wm = (unsigned)__builtin_amdgcn_readlane((int)m, 63);
        if (lane == r) mine = wm;
        if (k[0] == wm) {
            #pragma unroll
            for (int s = 0; s < 12; ++s) k[s] = k[s + 1];
        }
    }
    if (lane < 12) top[(size_t)(qoff + q) * NC + lane] = (int)(mine & 0xFFFFu);
}

// -------------------------------------------------------------- refine ------
// 16 lanes per query, 4 queries/wave, no LDS. Coalesced candidate-row loads,
// fp64 dots + width-16 butterfly reduce, rank-based order-free top-5
// (key = monotone-fp64 | reversed-idx tie-break; smaller idx wins ties like
// jax), softmax weights (0 for rank>=5), weighted sum over all 12 rows with
// compile-time register indexing. nf -> bf16.
__global__ __launch_bounds__(256) void k_refine(const float* __restrict__ feat,
        const float* __restrict__ bank, const int* __restrict__ top,
        const double* __restrict__ binv, short* __restrict__ nf)
{
    const int t = threadIdx.x, lane = t & 63, w = t >> 6;
    const int g = lane >> 4, u = lane & 15;
    const int q = blockIdx.x * 16 + w * 4 + g;

    int ci[NC];
    #pragma unroll
    for (int c = 0; c < NC; ++c) ci[c] = top[(size_t)q * NC + c];

    // query elements j*64 + u*4 .. +3  (contiguous 256B per 16-lane group)
    double qd[16];
    double ss = 0.0;
    #pragma unroll
    for (int j = 0; j < 4; ++j) {
        float4 v = *(const float4*)(feat + (size_t)q * DIM + j * 64 + u * 4);
        qd[j*4+0] = v.x; qd[j*4+1] = v.y; qd[j*4+2] = v.z; qd[j*4+3] = v.w;
        ss += (double)v.x*v.x + (double)v.y*v.y + (double)v.z*v.z + (double)v.w*v.w;
    }
    #pragma unroll
    for (int o = 1; o < 16; o <<= 1) ss += __shfl_xor(ss, o, 16);
    double n = sqrt(ss); if (n < 1e-12) n = 1e-12;
    const double qi = 1.0 / n;

    // fp64 partial dots (coalesced row loads), butterfly reduce within group
    double s[NC];
    #pragma unroll
    for (int c = 0; c < NC; ++c) {
        const float* brow = bank + (size_t)ci[c] * DIM + u * 4;
        double acc = 0.0;
        #pragma unroll
        for (int j = 0; j < 4; ++j) {
            float4 b = *(const float4*)(brow + j * 64);
            acc += qd[j*4+0]*(double)b.x + qd[j*4+1]*(double)b.y
                 + qd[j*4+2]*(double)b.z + qd[j*4+3]*(double)b.w;
        }
        s[c] = acc;
    }
    #pragma unroll
    for (int o = 1; o < 16; o <<= 1)
        #pragma unroll
        for (int c = 0; c < NC; ++c) s[c] += __shfl_xor(s[c], o, 16);

    // scaled sims, sortable keys, fp32 copies for softmax
    unsigned long long key[NC];
    float vf[NC];
    #pragma unroll
    for (int c = 0; c < NC; ++c) {
        double v = s[c] * qi * binv[ci[c]];
        vf[c] = (float)v;
        unsigned long long b = __builtin_bit_cast(unsigned long long, v);
        unsigned long long m = (b >> 63) ? ~b : (b | 0x8000000000000000ULL);
        key[c] = (m & ~0x3FFULL) | (unsigned long long)(1023 - ci[c]);
    }

    // ranks via 66 pairwise comparisons (keys all distinct)
    int rank[NC];
    #pragma unroll
    for (int c = 0; c < NC; ++c) rank[c] = 0;
    #pragma unroll
    for (int c1 = 0; c1 < NC; ++c1)
        #pragma unroll
        for (int c2 = c1 + 1; c2 < NC; ++c2) {
            const bool gt = key[c1] > key[c2];
            rank[c2] += gt ? 1 : 0;
            rank[c1] += gt ? 0 : 1;
        }

    // softmax over rank<5 (max over all 12 == top-1, which is in the set)
    float vm = vf[0];
    #pragma unroll
    for (int c = 1; c < NC; ++c) vm = fmaxf(vm, vf[c]);
    float e[NC]; float wsum = 0.f;
    #pragma unroll
    for (int c = 0; c < NC; ++c) {
        float ex = __expf(vf[c] - vm);
        ex = (rank[c] < 5) ? ex : 0.f;
        e[c] = ex; wsum += ex;
    }
    const float inv = 1.f / wsum;

    asm volatile("" ::: "memory");   // don't CSE-cache 48 row loads from phase 2

    float4 oa[4];
    #pragma unroll
    for (int j = 0; j < 4; ++j) { oa[j].x = 0.f; oa[j].y = 0.f; oa[j].z = 0.f; oa[j].w = 0.f; }
    #pragma unroll
    for (int c = 0; c < NC; ++c) {
        const float wc = e[c] * inv;
        const float* brow = bank + (size_t)ci[c] * DIM + u * 4;
        #pragma unroll
        for (int j = 0; j < 4; ++j) {
            float4 b = *(const float4*)(brow + j * 64);
            oa[j].x += wc * b.x; oa[j].y += wc * b.y;
            oa[j].z += wc * b.z; oa[j].w += wc * b.w;
        }
    }
    short* od = nf + (size_t)q * DIM + u * 4;
    #pragma unroll
    for (int j = 0; j < 4; ++j) {
        uint2 pk;
        pk.x = ((unsigned)(unsigned short)f32bf(oa[j].x)) |
               (((unsigned)(unsigned short)f32bf(oa[j].y)) << 16);
        pk.y = ((unsigned)(unsigned short)f32bf(oa[j].z)) |
               (((unsigned)(unsigned short)f32bf(oa[j].w)) << 16);
        *(uint2*)(od + j * 64) = pk;
    }
}

// --------------------------------------------------------------- MLP 1 ------
__global__ __launch_bounds__(256) void k_mlp1(const float* __restrict__ feat,
        const short* __restrict__ nf, const short* __restrict__ w1bf,
        const float* __restrict__ b1, short* __restrict__ h)
{
    __shared__ alignas(16) short As[128 * 40];
    __shared__ alignas(16) short Bs[128 * 40];
    const int t = threadIdx.x, lane = t & 63, w = t >> 6;
    const int mb = (blockIdx.x >> 1) * 128;
    const int nb = (blockIdx.x & 1) * 128;
    const int r = t >> 1, hh = t & 1;
    const int mwb = (w >> 1) * 64, nwb = (w & 1) * 64;
    const f32x4 vzero = {0.f, 0.f, 0.f, 0.f};

    f32x4 acc[4][4];
    #pragma unroll
    for (int a = 0; a < 4; ++a)
        #pragma unroll
        for (int b = 0; b < 4; ++b) acc[a][b] = vzero;

    for (int kc = 0; kc < 16; ++kc) {
        short* ad = As + r * 40 + hh * 16;
        if (kc < 8) {
            const float4* s = (const float4*)(feat + (size_t)(mb + r) * 256 + kc * 32 + hh * 16);
            #pragma unroll
            for (int i = 0; i < 4; ++i) {
                float4 v = s[i];
                ad[i*4+0] = f32bf(v.x); ad[i*4+1] = f32bf(v.y);
                ad[i*4+2] = f32bf(v.z); ad[i*4+3] = f32bf(v.w);
            }
        } else {
            const uint4* s = (const uint4*)(nf + (size_t)(mb + r) * 256 + (kc - 8) * 32 + hh * 16);
            *(uint4*)ad = s[0]; *(uint4*)(ad + 8) = s[1];
        }
        {
            const uint4* bsrc = (const uint4*)(w1bf + (size_t)(nb + r) * 512 + kc * 32 + hh * 16);
            short* bd = Bs + r * 40 + hh * 16;
            *(uint4*)bd = bsrc[0]; *(uint4*)(bd + 8) = bsrc[1];
        }
        __syncthreads();
        short8 af[4], bf[4];
        const int ko = (lane >> 4) << 3;
        #pragma unroll
        for (int mt = 0; mt < 4; ++mt)
            af[mt] = *(const short8*)(As + (mwb + mt * 16 + (lane & 15)) * 40 + ko);
        #pragma unroll
        for (int nt = 0; nt < 4; ++nt)
            bf[nt] = *(const short8*)(Bs + (nwb + nt * 16 + (lane & 15)) * 40 + ko);
        #pragma unroll
        for (int mt = 0; mt < 4; ++mt)
            #pragma unroll
            for (int nt = 0; nt < 4; ++nt)
                acc[mt][nt] = __builtin_amdgcn_mfma_f32_16x16x32_bf16(af[mt], bf[nt], acc[mt][nt], 0, 0, 0);
        __syncthreads();
    }
    {
        const int rq = (lane >> 4) << 2;
        const int cc = lane & 15;
        #pragma unroll
        for (int mt = 0; mt < 4; ++mt)
            #pragma unroll
            for (int nt = 0; nt < 4; ++nt) {
                const int row = mb + mwb + mt * 16 + rq;
                const int col = nb + nwb + nt * 16 + cc;
                const float bias = b1[col];
                #pragma unroll
                for (int rr = 0; rr < 4; ++rr) {
                    float v = acc[mt][nt][rr] + bias;
                    v = fmaxf(v, 0.f);
                    h[(size_t)(row + rr) * 256 + col] = f32bf(v);
                }
            }
    }
}

// --------------------------------------------------------------- MLP 2 ------
__global__ __launch_bounds__(256) void k_mlp2(const short* __restrict__ h,
        const short* __restrict__ w2bf, const float* __restrict__ b2,
        float* __restrict__ out)
{
    __shared__ alignas(16) short As[128 * 40];
    __shared__ alignas(16) short Bs[128 * 40];
    const int t = threadIdx.x, lane = t & 63, w = t >> 6;
    const int mb = (blockIdx.x >> 1) * 128;
    const int nb = (blockIdx.x & 1) * 128;
    const int r = t >> 1, hh = t & 1;
    const int mwb = (w >> 1) * 64, nwb = (w & 1) * 64;
    const f32x4 vzero = {0.f, 0.f, 0.f, 0.f};

    f32x4 acc[4][4];
    #pragma unroll
    for (int a = 0; a < 4; ++a)
        #pragma unroll
        for (int b = 0; b < 4; ++b) acc[a][b] = vzero;

    for (int kc = 0; kc < 8; ++kc) {
        {
            const uint4* s = (const uint4*)(h + (size_t)(mb + r) * 256 + kc * 32 + hh * 16);
            short* ad = As + r * 40 + hh * 16;
            *(uint4*)ad = s[0]; *(uint4*)(ad + 8) = s[1];
        }
        {
            const uint4* bsrc = (const uint4*)(w2bf + (size_t)(nb + r) * 256 + kc * 32 + hh * 16);
            short* bd = Bs + r * 40 + hh * 16;
            *(uint4*)bd = bsrc[0]; *(uint4*)(bd + 8) = bsrc[1];
        }
        __syncthreads();
        short8 af[4], bf[4];
        const int ko = (lane >> 4) << 3;
        #pragma unroll
        for (int mt = 0; mt < 4; ++mt)
            af[mt] = *(const short8*)(As + (mwb + mt * 16 + (lane & 15)) * 40 + ko);
        #pragma unroll
        for (int nt = 0; nt < 4; ++nt)
            bf[nt] = *(const short8*)(Bs + (nwb + nt * 16 + (lane & 15)) * 40 + ko);
        #pragma unroll
        for (int mt = 0; mt < 4; ++mt)
            #pragma unroll
            for (int nt = 0; nt < 4; ++nt)
                acc[mt][nt] = __builtin_amdgcn_mfma_f32_16x16x32_bf16(af[mt], bf[nt], acc[mt][nt], 0, 0, 0);
        __syncthreads();
    }
    {
        const int rq = (lane >> 4) << 2;
        const int cc = lane & 15;
        #pragma unroll
        for (int mt = 0; mt < 4; ++mt)
            #pragma unroll
            for (int nt = 0; nt < 4; ++nt) {
                const int row = mb + mwb + mt * 16 + rq;
                const int col = nb + nwb + nt * 16 + cc;
                const float bias = b2[col];
                #pragma unroll
                for (int rr = 0; rr < 4; ++rr)
                    out[(size_t)(row + rr) * 256 + col] = acc[mt][nt][rr] + bias;
            }
    }
}

// ------------------------------------------------------------- launcher -----
extern "C" void kernel_launch(void* const* d_in, const int* in_sizes, int n_in,
                              void* d_out, int out_size, void* d_ws, size_t ws_size,
                              hipStream_t stream) {
    const float* feat = (const float*)d_in[0];
    const float* bank = (const float*)d_in[1];
    const float* W1   = (const float*)d_in[2];
    const float* b1   = (const float*)d_in[3];
    const float* W2   = (const float*)d_in[4];
    const float* b2   = (const float*)d_in[5];
    float* out = (float*)d_out;

    char* ws = (char*)d_ws;
    short*  bnbf = (short*)(ws + 0);              // 1024*256*2   = 524288
    double* binv = (double*)(ws + 524288);        // 1024*8       = 8192
    short*  w1bf = (short*)(ws + 532480);         // 131072*2     = 262144
    short*  w2bf = (short*)(ws + 794624);         // 65536*2      = 131072
    int*    top  = (int*)(ws + 925696);           // 65536*12*4   = 3145728
    short*  nf   = (short*)(ws + 4071424);        // 65536*256*2  = 33554432
    short*  X    = (short*)(ws + 37625856);       // 33554432: sims slices, then h
    // total 71180288 bytes

    k_prep<<<1792, 256, 0, stream>>>(bank, W1, W2, bnbf, binv, w1bf, w2bf);
    for (int s = 0; s < 4; ++s) {
        const int qoff = s * 16384;
        k_sims  <<<256,  256, 0, stream>>>(feat, bnbf, X, qoff);
        k_select<<<4096, 256, 0, stream>>>(X, top, qoff);
    }
    k_refine<<<4096, 256, 0, stream>>>(feat, bank, top, binv, nf);
    k_mlp1  <<<1024, 256, 0, stream>>>(feat, nf, w1bf, b1, (short*)X);
    k_mlp2  <<<1024, 256, 0, stream>>>((short*)X, w2bf, b2, out);
}